// Round 1
// baseline (12375.645 us; speedup 1.0000x reference)
//
#include <hip/hip_runtime.h>
#include <hip/hip_bf16.h>

#define HD 1024     // hidden dim
#define BB 512      // batch
#define SS 64       // seq len
#define N3 3072     // 3*H
#define ND 9        // n_drum_classes
#define VC 4        // vel_cond_dim

// ============================================================================
// Main step GEMM: C[512,3072] = A[512,1024] @ W[3072,1024]^T  (NT layout)
// 64x64 tile, 256 threads, 4x4 regs/thread, K-tile 32, transposed LDS staging.
// blockIdx.z selects (A0,W0,C0) or (A1,W1,C1) so gi2/gh2 run in one launch.
// ============================================================================
__global__ __launch_bounds__(256) void gemm_step(
    const float* __restrict__ A0, const float* __restrict__ W0, float* __restrict__ C0,
    const float* __restrict__ A1, const float* __restrict__ W1, float* __restrict__ C1)
{
    const float* A = blockIdx.z ? A1 : A0;
    const float* W = blockIdx.z ? W1 : W0;
    float*       C = blockIdx.z ? C1 : C0;

    __shared__ float As[32][68];   // [k][m], row = 68 floats -> 16B-aligned rows
    __shared__ float Ws[32][68];   // [k][n]

    const int tid = threadIdx.x;
    const int bm  = blockIdx.y * 64;
    const int bn  = blockIdx.x * 64;
    const int r   = tid >> 3;          // 0..31 staging row
    const int kq  = (tid & 7) << 2;    // 0,4,...,28
    const int ty  = tid >> 4;          // 0..15
    const int tx  = tid & 15;          // 0..15

    const float* Ar = A + (size_t)(bm + r) * HD;
    const float* Wr = W + (size_t)(bn + r) * HD;

    float acc[4][4] = {};

    for (int k0 = 0; k0 < HD; k0 += 32) {
        float4 a0 = *(const float4*)(Ar + k0 + kq);
        float4 a1 = *(const float4*)(Ar + 32 * HD + k0 + kq);
        float4 w0 = *(const float4*)(Wr + k0 + kq);
        float4 w1 = *(const float4*)(Wr + 32 * HD + k0 + kq);
        __syncthreads();
        As[kq+0][r]    = a0.x; As[kq+1][r]    = a0.y; As[kq+2][r]    = a0.z; As[kq+3][r]    = a0.w;
        As[kq+0][r+32] = a1.x; As[kq+1][r+32] = a1.y; As[kq+2][r+32] = a1.z; As[kq+3][r+32] = a1.w;
        Ws[kq+0][r]    = w0.x; Ws[kq+1][r]    = w0.y; Ws[kq+2][r]    = w0.z; Ws[kq+3][r]    = w0.w;
        Ws[kq+0][r+32] = w1.x; Ws[kq+1][r+32] = w1.y; Ws[kq+2][r+32] = w1.z; Ws[kq+3][r+32] = w1.w;
        __syncthreads();
        #pragma unroll
        for (int k = 0; k < 32; ++k) {
            float4 avv = *(const float4*)&As[k][ty * 4];
            float4 wvv = *(const float4*)&Ws[k][tx * 4];
            const float av[4] = {avv.x, avv.y, avv.z, avv.w};
            const float wv[4] = {wvv.x, wvv.y, wvv.z, wvv.w};
            #pragma unroll
            for (int i = 0; i < 4; ++i)
                #pragma unroll
                for (int j = 0; j < 4; ++j)
                    acc[i][j] = fmaf(av[i], wv[j], acc[i][j]);
        }
    }
    #pragma unroll
    for (int i = 0; i < 4; ++i) {
        float4 o = make_float4(acc[i][0], acc[i][1], acc[i][2], acc[i][3]);
        *(float4*)(C + (size_t)(bm + ty * 4 + i) * N3 + bn + tx * 4) = o;
    }
}

// ============================================================================
// Init: h1 = tanh(concat(z, note_encoded, genre) @ W_in^T + b_in)
// M=512, N=1024, K=784. Same tile structure, KT=16, gather-staged A.
// ============================================================================
__global__ __launch_bounds__(256) void init_h1(
    const float* __restrict__ z, const float* __restrict__ ne, const float* __restrict__ gc,
    const float* __restrict__ W_in, const float* __restrict__ b_in, float* __restrict__ h1)
{
    __shared__ float As[16][68];
    __shared__ float Ws[16][68];

    const int tid = threadIdx.x;
    const int bm  = blockIdx.y * 64;   // batch rows
    const int bn  = blockIdx.x * 64;   // hidden cols
    const int r   = tid >> 2;          // 0..63
    const int kq  = (tid & 3) << 2;    // 0,4,8,12
    const int ty  = tid >> 4;
    const int tx  = tid & 15;
    const int brow = bm + r;

    float acc[4][4] = {};

    for (int k0 = 0; k0 < 784; k0 += 16) {
        const int c = k0 + kq;
        float4 a;
        if (c < 256)      a = *(const float4*)(z  + (size_t)brow * 256 + c);
        else if (c < 768) a = *(const float4*)(ne + (size_t)brow * 512 + (c - 256));
        else              a = *(const float4*)(gc + (size_t)brow * 16  + (c - 768));
        float4 w = *(const float4*)(W_in + (size_t)(bn + r) * 784 + c);
        __syncthreads();
        As[kq+0][r] = a.x; As[kq+1][r] = a.y; As[kq+2][r] = a.z; As[kq+3][r] = a.w;
        Ws[kq+0][r] = w.x; Ws[kq+1][r] = w.y; Ws[kq+2][r] = w.z; Ws[kq+3][r] = w.w;
        __syncthreads();
        #pragma unroll
        for (int k = 0; k < 16; ++k) {
            float4 avv = *(const float4*)&As[k][ty * 4];
            float4 wvv = *(const float4*)&Ws[k][tx * 4];
            const float av[4] = {avv.x, avv.y, avv.z, avv.w};
            const float wv[4] = {wvv.x, wvv.y, wvv.z, wvv.w};
            #pragma unroll
            for (int i = 0; i < 4; ++i)
                #pragma unroll
                for (int j = 0; j < 4; ++j)
                    acc[i][j] = fmaf(av[i], wv[j], acc[i][j]);
        }
    }
    const int col = bn + tx * 4;
    float4 bi = *(const float4*)(b_in + col);
    const float bv[4] = {bi.x, bi.y, bi.z, bi.w};
    #pragma unroll
    for (int i = 0; i < 4; ++i) {
        float4 o = make_float4(tanhf(acc[i][0] + bv[0]), tanhf(acc[i][1] + bv[1]),
                               tanhf(acc[i][2] + bv[2]), tanhf(acc[i][3] + bv[3]));
        *(float4*)(h1 + (size_t)(bm + ty * 4 + i) * HD + col) = o;
    }
}

// ============================================================================
// GRU1 pointwise: computes x-side gates on the fly (K=22) + combine.
// h1 <- GRU(inp, h1);  if step==0: h2 <- h1
// grid (4, 512), 256 threads: thread = (b=blockIdx.y, jj=blockIdx.x*256+tid)
// ============================================================================
__global__ __launch_bounds__(256) void gru1_pw(
    const float* __restrict__ gh1, float* __restrict__ h1, float* __restrict__ h2,
    const float* __restrict__ note, const float* __restrict__ velc,
    const float* __restrict__ dout,
    const float* __restrict__ W_ih1, const float* __restrict__ b_ih1,
    const float* __restrict__ b_hh1, int step)
{
    __shared__ float inp[22];
    const int b  = blockIdx.y;
    const int jj = blockIdx.x * 256 + threadIdx.x;

    if (threadIdx.x < 22) {
        const int c = threadIdx.x;
        float v;
        if (c < 9)       v = (step == 0) ? 0.f : dout[(size_t)b * (SS * ND) + (step - 1) * ND + c];
        else if (c < 18) v = note[(size_t)b * (SS * ND) + step * ND + (c - 9)];
        else             v = velc[(size_t)b * (SS * VC) + step * VC + (c - 18)];
        inp[c] = v;
    }
    __syncthreads();

    float ir = b_ih1[jj], iz = b_ih1[HD + jj], inn = b_ih1[2 * HD + jj];
    const float* w0 = W_ih1 + (size_t)jj * 22;
    const float* w1 = W_ih1 + (size_t)(HD + jj) * 22;
    const float* w2 = W_ih1 + (size_t)(2 * HD + jj) * 22;
    #pragma unroll
    for (int c = 0; c < 22; ++c) {
        const float x = inp[c];
        ir  = fmaf(x, w0[c], ir);
        iz  = fmaf(x, w1[c], iz);
        inn = fmaf(x, w2[c], inn);
    }

    const float* g = gh1 + (size_t)b * N3;
    const float hr = g[jj]          + b_hh1[jj];
    const float hz = g[HD + jj]     + b_hh1[HD + jj];
    const float hn = g[2 * HD + jj] + b_hh1[2 * HD + jj];

    const float rg = 1.f / (1.f + __expf(-(ir + hr)));
    const float zg = 1.f / (1.f + __expf(-(iz + hz)));
    const float n  = tanhf(inn + rg * hn);
    const float hold = h1[(size_t)b * HD + jj];
    const float hnew = (1.f - zg) * n + zg * hold;
    h1[(size_t)b * HD + jj] = hnew;
    if (step == 0) h2[(size_t)b * HD + jj] = hnew;
}

// ============================================================================
// GRU2 pointwise: h2 <- GRU(h1, h2) given gi2 = h1@W_ih2^T, gh2 = h2@W_hh2^T
// ============================================================================
__global__ __launch_bounds__(256) void gru2_pw(
    const float* __restrict__ gi2, const float* __restrict__ gh2, float* __restrict__ h2,
    const float* __restrict__ b_ih2, const float* __restrict__ b_hh2)
{
    const int b  = blockIdx.y;
    const int jj = blockIdx.x * 256 + threadIdx.x;
    const float* gi = gi2 + (size_t)b * N3;
    const float* gh = gh2 + (size_t)b * N3;

    const float ir = gi[jj]          + b_ih2[jj];
    const float hr = gh[jj]          + b_hh2[jj];
    const float iz = gi[HD + jj]     + b_ih2[HD + jj];
    const float hz = gh[HD + jj]     + b_hh2[HD + jj];
    const float inn = gi[2 * HD + jj] + b_ih2[2 * HD + jj];
    const float hn  = gh[2 * HD + jj] + b_hh2[2 * HD + jj];

    const float rg = 1.f / (1.f + __expf(-(ir + hr)));
    const float zg = 1.f / (1.f + __expf(-(iz + hz)));
    const float n  = tanhf(inn + rg * hn);
    const float hold = h2[(size_t)b * HD + jj];
    h2[(size_t)b * HD + jj] = (1.f - zg) * n + zg * hold;
}

// ============================================================================
// Output projection: out[b, step, :] = sigmoid(h2[b,:] @ W_out^T + b_out)
// One wave (64 lanes) per batch row; 9 accumulators; wave shuffle reduce.
// ============================================================================
__global__ __launch_bounds__(64) void outproj(
    const float* __restrict__ h2, const float* __restrict__ W_out,
    const float* __restrict__ b_out, float* __restrict__ dout, int step)
{
    const int b = blockIdx.x;
    const int t = threadIdx.x;
    float acc[ND] = {};
    const float* hb = h2 + (size_t)b * HD;
    for (int k = t; k < HD; k += 64) {
        const float hv = hb[k];
        #pragma unroll
        for (int d = 0; d < ND; ++d) acc[d] = fmaf(hv, W_out[d * HD + k], acc[d]);
    }
    #pragma unroll
    for (int d = 0; d < ND; ++d) {
        #pragma unroll
        for (int off = 32; off > 0; off >>= 1) acc[d] += __shfl_down(acc[d], off);
    }
    if (t == 0) {
        #pragma unroll
        for (int d = 0; d < ND; ++d)
            dout[(size_t)b * (SS * ND) + step * ND + d] =
                1.f / (1.f + __expf(-(acc[d] + b_out[d])));
    }
}

// ============================================================================
extern "C" void kernel_launch(void* const* d_in, const int* in_sizes, int n_in,
                              void* d_out, int out_size, void* d_ws, size_t ws_size,
                              hipStream_t stream)
{
    const float* z     = (const float*)d_in[0];
    const float* ne    = (const float*)d_in[1];
    // d_in[2] = vel_target, unused in eval mode
    const float* note  = (const float*)d_in[3];
    const float* velc  = (const float*)d_in[4];
    const float* gc    = (const float*)d_in[5];
    const float* W_in  = (const float*)d_in[6];
    const float* b_in  = (const float*)d_in[7];
    const float* W_ih1 = (const float*)d_in[8];
    const float* W_hh1 = (const float*)d_in[9];
    const float* b_ih1 = (const float*)d_in[10];
    const float* b_hh1 = (const float*)d_in[11];
    const float* W_ih2 = (const float*)d_in[12];
    const float* W_hh2 = (const float*)d_in[13];
    const float* b_ih2 = (const float*)d_in[14];
    const float* b_hh2 = (const float*)d_in[15];
    const float* W_out = (const float*)d_in[16];
    const float* b_out = (const float*)d_in[17];
    float* out = (float*)d_out;

    float* h1  = (float*)d_ws;         // [512,1024]
    float* h2  = h1  + BB * HD;        // [512,1024]
    float* gh1 = h2  + BB * HD;        // [512,3072]
    float* gi2 = gh1 + (size_t)BB * N3;// [512,3072]
    float* gh2 = gi2 + (size_t)BB * N3;// [512,3072]
    // total: 23.1 MB of workspace

    init_h1<<<dim3(16, 8), 256, 0, stream>>>(z, ne, gc, W_in, b_in, h1);

    for (int s = 0; s < SS; ++s) {
        // gh1 = h1 @ W_hh1^T
        gemm_step<<<dim3(48, 8, 1), 256, 0, stream>>>(h1, W_hh1, gh1, h1, W_hh1, gh1);
        // h1 <- GRU1(inp, h1); h2 <- h1 at step 0
        gru1_pw<<<dim3(4, BB), 256, 0, stream>>>(gh1, h1, h2, note, velc, out,
                                                 W_ih1, b_ih1, b_hh1, s);
        // gi2 = h1 @ W_ih2^T ; gh2 = h2 @ W_hh2^T   (dual launch via z)
        gemm_step<<<dim3(48, 8, 2), 256, 0, stream>>>(h1, W_ih2, gi2, h2, W_hh2, gh2);
        // h2 <- GRU2(h1, h2)
        gru2_pw<<<dim3(4, BB), 256, 0, stream>>>(gi2, gh2, h2, b_ih2, b_hh2);
        // out[:, s, :] = sigmoid(h2 @ W_out^T + b_out)
        outproj<<<dim3(BB), 64, 0, stream>>>(h2, W_out, b_out, out, s);
    }
}

// Round 2
// 2149.546 us; speedup vs baseline: 5.7573x; 5.7573x over previous
//
#include <hip/hip_runtime.h>
#include <hip/hip_bf16.h>

#define HD 1024
#define BB 512
#define SS 64
#define N3 3072
#define NC 9216      // 3 * N3  (gi2 | gh1 | gh2)
#define ND 9
#define VC 4

typedef __attribute__((ext_vector_type(8))) short bf16x8;
typedef __attribute__((ext_vector_type(4))) float f32x4;

__device__ __forceinline__ ushort f2b(float f) {
    unsigned u = __builtin_bit_cast(unsigned, f);
    u += 0x7fffu + ((u >> 16) & 1u);          // round-to-nearest-even
    return (ushort)(u >> 16);
}

__device__ __forceinline__ void gld_lds16(const void* g, void* l) {
    __builtin_amdgcn_global_load_lds(
        (const __attribute__((address_space(1))) unsigned int*)g,
        (__attribute__((address_space(3))) unsigned int*)l, 16, 0, 0);
}

// ============================================================================
// prep: W_cat bf16 = [W_ih2 ; W_hh1 ; W_hh2], each [3072][1024]
// grid (9216), 256 thr: one row per block, 4 f32 per thread.
// ============================================================================
__global__ __launch_bounds__(256) void prep_w(
    const float* __restrict__ Wih2, const float* __restrict__ Whh1,
    const float* __restrict__ Whh2, ushort* __restrict__ Wcat)
{
    const int row = blockIdx.x;
    const float* src = row < 3072 ? Wih2 + (size_t)row * HD
                     : row < 6144 ? Whh1 + (size_t)(row - 3072) * HD
                                  : Whh2 + (size_t)(row - 6144) * HD;
    const int c = threadIdx.x * 4;
    float4 v = *(const float4*)(src + c);
    ushort4 o;
    o.x = f2b(v.x); o.y = f2b(v.y); o.z = f2b(v.z); o.w = f2b(v.w);
    *(ushort4*)(Wcat + (size_t)row * HD + c) = o;
}

// Wt1[c][g] = W_ih1[g][c]   (22 x 3072, f32) — for coalesced gru1 reads
__global__ __launch_bounds__(256) void prep_wt1(
    const float* __restrict__ Wih1, float* __restrict__ Wt1)
{
    const int g = blockIdx.x * 256 + threadIdx.x;   // 0..3071
    #pragma unroll
    for (int c = 0; c < 22; ++c)
        Wt1[c * N3 + g] = Wih1[(size_t)g * 22 + c];
}

// ============================================================================
// init: h1 = tanh(concat(z, note_encoded, genre) @ W_in^T + b_in)  (f32 path)
// also writes bf16 shadow h1b.
// ============================================================================
__global__ __launch_bounds__(256) void init_h1(
    const float* __restrict__ z, const float* __restrict__ ne, const float* __restrict__ gc,
    const float* __restrict__ W_in, const float* __restrict__ b_in,
    float* __restrict__ h1, ushort* __restrict__ h1b)
{
    __shared__ float As[16][68];
    __shared__ float Ws[16][68];

    const int tid = threadIdx.x;
    const int bm  = blockIdx.y * 64;
    const int bn  = blockIdx.x * 64;
    const int r   = tid >> 2;
    const int kq  = (tid & 3) << 2;
    const int ty  = tid >> 4;
    const int tx  = tid & 15;
    const int brow = bm + r;

    float acc[4][4] = {};

    for (int k0 = 0; k0 < 784; k0 += 16) {
        const int c = k0 + kq;
        float4 a;
        if (c < 256)      a = *(const float4*)(z  + (size_t)brow * 256 + c);
        else if (c < 768) a = *(const float4*)(ne + (size_t)brow * 512 + (c - 256));
        else              a = *(const float4*)(gc + (size_t)brow * 16  + (c - 768));
        float4 w = *(const float4*)(W_in + (size_t)(bn + r) * 784 + c);
        __syncthreads();
        As[kq+0][r] = a.x; As[kq+1][r] = a.y; As[kq+2][r] = a.z; As[kq+3][r] = a.w;
        Ws[kq+0][r] = w.x; Ws[kq+1][r] = w.y; Ws[kq+2][r] = w.z; Ws[kq+3][r] = w.w;
        __syncthreads();
        #pragma unroll
        for (int k = 0; k < 16; ++k) {
            float4 avv = *(const float4*)&As[k][ty * 4];
            float4 wvv = *(const float4*)&Ws[k][tx * 4];
            const float av[4] = {avv.x, avv.y, avv.z, avv.w};
            const float wv[4] = {wvv.x, wvv.y, wvv.z, wvv.w};
            #pragma unroll
            for (int i = 0; i < 4; ++i)
                #pragma unroll
                for (int j = 0; j < 4; ++j)
                    acc[i][j] = fmaf(av[i], wv[j], acc[i][j]);
        }
    }
    const int col = bn + tx * 4;
    float4 bi = *(const float4*)(b_in + col);
    const float bv[4] = {bi.x, bi.y, bi.z, bi.w};
    #pragma unroll
    for (int i = 0; i < 4; ++i) {
        const int row = bm + ty * 4 + i;
        float4 o = make_float4(tanhf(acc[i][0] + bv[0]), tanhf(acc[i][1] + bv[1]),
                               tanhf(acc[i][2] + bv[2]), tanhf(acc[i][3] + bv[3]));
        *(float4*)(h1 + (size_t)row * HD + col) = o;
        ushort4 ob; ob.x = f2b(o.x); ob.y = f2b(o.y); ob.z = f2b(o.z); ob.w = f2b(o.w);
        *(ushort4*)(h1b + (size_t)row * HD + col) = ob;
    }
}

// ============================================================================
// MFMA GEMM: C[512, 9216] over three sections sharing one launch.
//   cols 0..3071   : gi2  = h1b @ W_ih2^T
//   cols 3072..6143: gh1' = h1b @ W_hh1^T   (for the NEXT step)
//   cols 6144..9215: gh2  = h2b @ W_hh2^T
// 64x64 tile, BK=64, 4 waves, mfma_f32_16x16x32_bf16,
// global_load_lds w16 + XOR-swizzled source, XCD-bijective block swizzle.
// grid (8, NT) with NT%8==0;  n-tile = swizzled + ntb.
// ============================================================================
__global__ __launch_bounds__(256) void gemm3(
    const ushort* __restrict__ h1b, const ushort* __restrict__ h2b,
    const ushort* __restrict__ Wcat, float* __restrict__ Cbuf, int ntb)
{
    __shared__ __align__(16) ushort As[4096];   // [64][64] linear
    __shared__ __align__(16) ushort Ws[4096];

    // XCD-aware bijective swizzle: each XCD gets a contiguous chunk of n-tiles
    const int flat = blockIdx.x + (blockIdx.y << 3);
    const int id   = (flat & 7) * gridDim.y + (flat >> 3);
    const int bm   = (id & 7) << 6;
    const int nt   = (id >> 3) + ntb;          // global n-tile 0..143

    const ushort* Amat = (nt < 96) ? h1b : h2b;
    const ushort* W    = Wcat + (size_t)(nt << 6) * HD;

    const int tid = threadIdx.x;
    const int w   = tid >> 6;
    const int l   = tid & 63;

    // staging: lane l covers (row_in_8 = l>>3, chunk = l&7); source chunk XOR-swizzled
    const int srow = l >> 3;
    const int sch  = ((l & 7) ^ srow) << 3;    // element offset of 16B chunk
    const ushort* Ag0 = Amat + (size_t)(bm + 16 * w + srow) * HD + sch;
    const ushort* Ag1 = Ag0 + 8 * HD;
    const ushort* Wg0 = W + (size_t)(16 * w + srow) * HD + sch;
    const ushort* Wg1 = Wg0 + 8 * HD;
    ushort* Al0 = As + (16 * w) * 64;          // wave-uniform LDS bases
    ushort* Al1 = As + (16 * w + 8) * 64;
    ushort* Wl0 = Ws + (16 * w) * 64;
    ushort* Wl1 = Ws + (16 * w + 8) * 64;

    const int wm = (w >> 1) << 5;              // 0 / 32
    const int wn = (w & 1) << 5;
    const int fr = l & 15;
    const int fc = l >> 4;                     // 0..3

    const int ra0 = wm + fr,  ra1 = wm + 16 + fr;
    const int rb0 = wn + fr,  rb1 = wn + 16 + fr;

    f32x4 acc00 = {0.f,0.f,0.f,0.f}, acc01 = {0.f,0.f,0.f,0.f};
    f32x4 acc10 = {0.f,0.f,0.f,0.f}, acc11 = {0.f,0.f,0.f,0.f};

    for (int kt = 0; kt < 16; ++kt) {
        const int ko = kt << 6;                // element offset in K
        __syncthreads();
        gld_lds16(Ag0 + ko, Al0);
        gld_lds16(Ag1 + ko, Al1);
        gld_lds16(Wg0 + ko, Wl0);
        gld_lds16(Wg1 + ko, Wl1);
        __syncthreads();                       // drains vmcnt before reads
        #pragma unroll
        for (int kk = 0; kk < 2; ++kk) {
            const int c = (kk << 2) + fc;
            bf16x8 a0 = *(const bf16x8*)(As + ra0 * 64 + ((c ^ (ra0 & 7)) << 3));
            bf16x8 a1 = *(const bf16x8*)(As + ra1 * 64 + ((c ^ (ra1 & 7)) << 3));
            bf16x8 b0 = *(const bf16x8*)(Ws + rb0 * 64 + ((c ^ (rb0 & 7)) << 3));
            bf16x8 b1 = *(const bf16x8*)(Ws + rb1 * 64 + ((c ^ (rb1 & 7)) << 3));
            acc00 = __builtin_amdgcn_mfma_f32_16x16x32_bf16(a0, b0, acc00, 0, 0, 0);
            acc01 = __builtin_amdgcn_mfma_f32_16x16x32_bf16(a0, b1, acc01, 0, 0, 0);
            acc10 = __builtin_amdgcn_mfma_f32_16x16x32_bf16(a1, b0, acc10, 0, 0, 0);
            acc11 = __builtin_amdgcn_mfma_f32_16x16x32_bf16(a1, b1, acc11, 0, 0, 0);
        }
    }

    const int bn = nt << 6;
    float* Cw = Cbuf + (size_t)(bm + wm) * NC + bn + wn;
    #pragma unroll
    for (int r = 0; r < 4; ++r) {
        const size_t ro0 = (size_t)(fc * 4 + r) * NC;
        const size_t ro1 = (size_t)(16 + fc * 4 + r) * NC;
        Cw[ro0 + fr]      = acc00[r];
        Cw[ro0 + 16 + fr] = acc01[r];
        Cw[ro1 + fr]      = acc10[r];
        Cw[ro1 + 16 + fr] = acc11[r];
    }
}

// ============================================================================
// GRU1: h1 <- GRU(inp, h1); x-side gates computed on the fly (K=22, Wt1).
// Also writes bf16 shadow; at step 0 copies h1->h2 (f32 + bf16).
// grid (512) x 1024 threads.
// ============================================================================
__global__ __launch_bounds__(1024) void gru1_f(
    const float* __restrict__ Cbuf, float* __restrict__ h1, ushort* __restrict__ h1b,
    float* __restrict__ h2, ushort* __restrict__ h2b,
    const float* __restrict__ note, const float* __restrict__ velc,
    const float* __restrict__ dout,
    const float* __restrict__ Wt1, const float* __restrict__ b_ih1,
    const float* __restrict__ b_hh1, int step)
{
    __shared__ float inp[22];
    const int b = blockIdx.x;
    const int j = threadIdx.x;

    if (j < 22) {
        float v;
        if (j < 9)       v = (step == 0) ? 0.f : dout[(size_t)b * (SS * ND) + (step - 1) * ND + j];
        else if (j < 18) v = note[(size_t)b * (SS * ND) + step * ND + (j - 9)];
        else             v = velc[(size_t)b * (SS * VC) + step * VC + (j - 18)];
        inp[j] = v;
    }
    __syncthreads();

    float ir = b_ih1[j], iz = b_ih1[HD + j], inn = b_ih1[2 * HD + j];
    #pragma unroll
    for (int c = 0; c < 22; ++c) {
        const float x = inp[c];
        const float* wr = Wt1 + c * N3;
        ir  = fmaf(x, wr[j],          ir);
        iz  = fmaf(x, wr[HD + j],     iz);
        inn = fmaf(x, wr[2 * HD + j], inn);
    }

    const float* g = Cbuf + (size_t)b * NC + N3;     // gh1 section
    const float hr = g[j]          + b_hh1[j];
    const float hz = g[HD + j]     + b_hh1[HD + j];
    const float hn = g[2 * HD + j] + b_hh1[2 * HD + j];

    const float rg = 1.f / (1.f + __expf(-(ir + hr)));
    const float zg = 1.f / (1.f + __expf(-(iz + hz)));
    const float n  = tanhf(inn + rg * hn);
    const float hnew = (1.f - zg) * n + zg * h1[(size_t)b * HD + j];
    h1[(size_t)b * HD + j]  = hnew;
    const ushort hb = f2b(hnew);
    h1b[(size_t)b * HD + j] = hb;
    if (step == 0) {
        h2[(size_t)b * HD + j]  = hnew;
        h2b[(size_t)b * HD + j] = hb;
    }
}

// ============================================================================
// GRU2 + output projection fused. grid (512) x 1024 threads.
// h2 <- GRU(h1, h2);  out[b,step,:] = sigmoid(h2 @ W_out^T + b_out)
// ============================================================================
__global__ __launch_bounds__(1024) void gru2_out(
    const float* __restrict__ Cbuf, float* __restrict__ h2, ushort* __restrict__ h2b,
    const float* __restrict__ b_ih2, const float* __restrict__ b_hh2,
    const float* __restrict__ W_out, const float* __restrict__ b_out,
    float* __restrict__ dout, int step)
{
    __shared__ float hs[HD];
    const int b = blockIdx.x;
    const int j = threadIdx.x;

    const float* gi = Cbuf + (size_t)b * NC;          // gi2
    const float* gh = Cbuf + (size_t)b * NC + 2 * N3; // gh2

    const float ir  = gi[j]          + b_ih2[j];
    const float hr  = gh[j]          + b_hh2[j];
    const float iz  = gi[HD + j]     + b_ih2[HD + j];
    const float hz  = gh[HD + j]     + b_hh2[HD + j];
    const float inn = gi[2 * HD + j] + b_ih2[2 * HD + j];
    const float hn  = gh[2 * HD + j] + b_hh2[2 * HD + j];

    const float rg = 1.f / (1.f + __expf(-(ir + hr)));
    const float zg = 1.f / (1.f + __expf(-(iz + hz)));
    const float n  = tanhf(inn + rg * hn);
    const float hnew = (1.f - zg) * n + zg * h2[(size_t)b * HD + j];
    h2[(size_t)b * HD + j]  = hnew;
    h2b[(size_t)b * HD + j] = f2b(hnew);
    hs[j] = hnew;
    __syncthreads();

    const int w = j >> 6;        // wave id 0..15
    const int t = j & 63;
    if (w < ND) {
        float a = 0.f;
        const float* wr = W_out + (size_t)w * HD;
        #pragma unroll
        for (int k = 0; k < HD / 64; ++k)
            a = fmaf(hs[t + k * 64], wr[t + k * 64], a);
        #pragma unroll
        for (int off = 32; off > 0; off >>= 1) a += __shfl_down(a, off);
        if (t == 0)
            dout[(size_t)b * (SS * ND) + step * ND + w] =
                1.f / (1.f + __expf(-(a + b_out[w])));
    }
}

// ============================================================================
extern "C" void kernel_launch(void* const* d_in, const int* in_sizes, int n_in,
                              void* d_out, int out_size, void* d_ws, size_t ws_size,
                              hipStream_t stream)
{
    const float* z     = (const float*)d_in[0];
    const float* ne    = (const float*)d_in[1];
    const float* note  = (const float*)d_in[3];
    const float* velc  = (const float*)d_in[4];
    const float* gc    = (const float*)d_in[5];
    const float* W_in  = (const float*)d_in[6];
    const float* b_in  = (const float*)d_in[7];
    const float* W_ih1 = (const float*)d_in[8];
    const float* W_hh1 = (const float*)d_in[9];
    const float* b_ih1 = (const float*)d_in[10];
    const float* b_hh1 = (const float*)d_in[11];
    const float* W_ih2 = (const float*)d_in[12];
    const float* W_hh2 = (const float*)d_in[13];
    const float* b_ih2 = (const float*)d_in[14];
    const float* b_hh2 = (const float*)d_in[15];
    const float* W_out = (const float*)d_in[16];
    const float* b_out = (const float*)d_in[17];
    float* out = (float*)d_out;

    // workspace layout
    float* h1   = (float*)d_ws;                      // [512*1024]
    float* h2   = h1 + BB * HD;                      // [512*1024]
    float* Cbuf = h2 + BB * HD;                      // [512*9216]
    float* Wt1  = Cbuf + (size_t)BB * NC;            // [22*3072]
    ushort* h1b = (ushort*)(Wt1 + 22 * N3);          // [512*1024]
    ushort* h2b = h1b + BB * HD;                     // [512*1024]
    ushort* Wcat = h2b + BB * HD;                    // [9216*1024]
    // total ≈ 44.3 MB

    prep_w <<<dim3(NC), 256, 0, stream>>>(W_ih2, W_hh1, W_hh2, Wcat);
    prep_wt1<<<dim3(12), 256, 0, stream>>>(W_ih1, Wt1);
    init_h1<<<dim3(16, 8), 256, 0, stream>>>(z, ne, gc, W_in, b_in, h1, h1b);

    // prologue: gh1 for step 0  (n-tiles 48..95)
    gemm3<<<dim3(8, 48), 256, 0, stream>>>(h1b, h2b, Wcat, Cbuf, 48);

    for (int s = 0; s < SS; ++s) {
        gru1_f<<<dim3(BB), 1024, 0, stream>>>(Cbuf, h1, h1b, h2, h2b,
                                              note, velc, out, Wt1, b_ih1, b_hh1, s);
        // gi2(s) | gh1(s+1) | gh2(s)  in one launch (n-tiles 0..143)
        gemm3<<<dim3(8, 144), 256, 0, stream>>>(h1b, h2b, Wcat, Cbuf, 0);
        gru2_out<<<dim3(BB), 1024, 0, stream>>>(Cbuf, h2, h2b, b_ih2, b_hh2,
                                                W_out, b_out, out, s);
    }
}